// Round 4
// baseline (282.209 us; speedup 1.0000x reference)
//
#include <hip/hip_runtime.h>
#include <hip/hip_bf16.h>

typedef short s16x8 __attribute__((ext_vector_type(8)));
typedef float f32x4 __attribute__((ext_vector_type(4)));

static __device__ inline unsigned short f2bf(float f) {
    __hip_bfloat16 h = __float2bfloat16(f);
    return *reinterpret_cast<unsigned short*>(&h);
}

// ---------- prep: zero hist, wT[n][k]=bf16(w[k][n]), Xb = packed bf16(X) ----
__global__ __launch_bounds__(256) void prep_kernel(
    const float* __restrict__ X, const float* __restrict__ w,
    unsigned int* __restrict__ Xb, unsigned short* __restrict__ wT,
    int* __restrict__ hist, int N, int nx2)
{
    int i = blockIdx.x * 256 + threadIdx.x;
    if (i < nx2) {                       // nx2 = N*64 float2 packs
        float2 v = ((const float2*)X)[i];
        Xb[i] = (unsigned int)f2bf(v.x) | ((unsigned int)f2bf(v.y) << 16);
    }
    if (i < 16384) {
        int n = i >> 7, k = i & 127;
        wT[i] = f2bf(w[k * 128 + n]);
    }
    if (i < N) hist[i] = 0;
}

// ---------- CSR build ----------
__global__ __launch_bounds__(256) void hist_kernel(
    const int* __restrict__ B, int* __restrict__ hist, int E)
{
    int e = blockIdx.x * 256 + threadIdx.x;
    if (e < E) atomicAdd(&hist[B[e]], 1);
}

// block-local exclusive scan -> cursor; block totals -> blockSums
__global__ __launch_bounds__(256) void scan1_kernel(
    const int* __restrict__ hist, int* __restrict__ cursor,
    int* __restrict__ blockSums, int N)
{
    __shared__ int s[256];
    int tid = threadIdx.x;
    int i = blockIdx.x * 256 + tid;
    int v = (i < N) ? hist[i] : 0;
    s[tid] = v;
    __syncthreads();
    for (int off = 1; off < 256; off <<= 1) {
        int t = (tid >= off) ? s[tid - off] : 0;
        __syncthreads();
        s[tid] += t;
        __syncthreads();
    }
    if (i < N) cursor[i] = s[tid] - v;           // local exclusive
    if (tid == 255) blockSums[blockIdx.x] = s[255];
}

__global__ __launch_bounds__(512) void scan2_kernel(
    int* __restrict__ blockSums, int nb)
{
    __shared__ int s[512];
    int tid = threadIdx.x;
    int v = (tid < nb) ? blockSums[tid] : 0;
    s[tid] = v;
    __syncthreads();
    for (int off = 1; off < 512; off <<= 1) {
        int t = (tid >= off) ? s[tid - off] : 0;
        __syncthreads();
        s[tid] += t;
        __syncthreads();
    }
    if (tid < nb) blockSums[tid] = s[tid] - v;   // exclusive across blocks
}

// scan3 folded in: global pos = local atomic slot + scanned block base
__global__ __launch_bounds__(256) void fill_kernel(
    const int* __restrict__ A, const int* __restrict__ B,
    int* __restrict__ cursor, const int* __restrict__ blockSums,
    int* __restrict__ csr_src, int E)
{
    int e = blockIdx.x * 256 + threadIdx.x;
    if (e < E) {
        int d = B[e];
        int pos = atomicAdd(&cursor[d], 1) + blockSums[d >> 8];
        csr_src[pos] = A[e];
    }
}

// ---------- fused aggregate + GEMM ----------
// Block = 256 thr (4 waves), 64 node rows. Phase 1: wave w aggregates rows
// w*16..w*16+15 into LDS (packed bf16x2, row stride 68 uints so the phase-2
// ds_read_b128 A-frag reads are conflict-free). Phase 2: MFMA vs L2-hot wT.
// Waves touch only their own 16 rows -> NO __syncthreads anywhere.
__global__ __launch_bounds__(256) void aggemm_kernel(
    const unsigned int* __restrict__ Xb, const int* __restrict__ hist,
    const int* __restrict__ cursor, const int* __restrict__ bs,
    const int* __restrict__ csr_src, const unsigned short* __restrict__ wT,
    const float* __restrict__ b, float* __restrict__ out, int N)
{
    __shared__ unsigned int lds[64 * 68];        // 17.4 KB

    const int tid  = threadIdx.x;
    const int w    = tid >> 6;
    const int lane = tid & 63;
    const int m    = lane & 15;
    const int q    = lane >> 4;
    const int row0 = blockIdx.x * 64;

    // ---- phase 1: aggregate (lane owns cols 2*lane, 2*lane+1) ----
    #pragma unroll 1
    for (int t = 0; t < 16; ++t) {
        const int lrow = w * 16 + t;
        const int node = row0 + lrow;
        float ax = 0.f, ay = 0.f;
        if (node < N) {
            int deg = hist[node];
            int e   = cursor[node] + bs[node >> 8];
            int s   = e - deg;
            for (int base = s; base < e; base += 64) {
                int cnt = e - base; if (cnt > 64) cnt = 64;
                int idx = base + lane;
                int src_l = (idx < e) ? csr_src[idx] : 0;
                int j = 0;
                for (; j + 1 < cnt; j += 2) {     // 2 gathers in flight
                    int s0 = __shfl(src_l, j);
                    int s1 = __shfl(src_l, j + 1);
                    unsigned p0 = Xb[(size_t)s0 * 64 + lane];
                    unsigned p1 = Xb[(size_t)s1 * 64 + lane];
                    ax += __uint_as_float(p0 << 16);
                    ay += __uint_as_float(p0 & 0xFFFF0000u);
                    ax += __uint_as_float(p1 << 16);
                    ay += __uint_as_float(p1 & 0xFFFF0000u);
                }
                if (j < cnt) {
                    int s0 = __shfl(src_l, j);
                    unsigned p0 = Xb[(size_t)s0 * 64 + lane];
                    ax += __uint_as_float(p0 << 16);
                    ay += __uint_as_float(p0 & 0xFFFF0000u);
                }
            }
        }
        lds[lrow * 68 + lane] =
            (unsigned int)f2bf(ax) | ((unsigned int)f2bf(ay) << 16);
    }

    // ---- phase 2: 16-row MFMA tile per wave (own rows only) ----
    // A[m][k=q*8+s*32+j]: uints at row*68 + s*16 + q*4 (16B aligned)
    const unsigned int* arow = &lds[(w * 16 + m) * 68 + q * 4];
    s16x8 a[4];
    #pragma unroll
    for (int s = 0; s < 4; ++s)
        a[s] = *(const s16x8*)(arow + s * 16);

    f32x4 acc[8] = {};
    #pragma unroll
    for (int s = 0; s < 4; ++s) {
        #pragma unroll
        for (int c = 0; c < 8; ++c) {
            s16x8 bf = *(const s16x8*)&wT[(size_t)(c * 16 + m) * 128 + s * 32 + q * 8];
            acc[c] = __builtin_amdgcn_mfma_f32_16x16x32_bf16(a[s], bf, acc[c], 0, 0, 0);
        }
    }

    const int r0 = row0 + w * 16 + q * 4;
    #pragma unroll
    for (int c = 0; c < 8; ++c) {
        int col = c * 16 + m;
        float bias = b[col];
        #pragma unroll
        for (int r = 0; r < 4; ++r) {
            int row = r0 + r;
            if (row < N)
                out[(size_t)row * 128 + col] = acc[c][r] + bias;
        }
    }
}

extern "C" void kernel_launch(void* const* d_in, const int* in_sizes, int n_in,
                              void* d_out, int out_size, void* d_ws, size_t ws_size,
                              hipStream_t stream) {
    const float* X = (const float*)d_in[0];
    const int*   A = (const int*)d_in[1];
    const int*   B = (const int*)d_in[2];
    const float* w = (const float*)d_in[3];
    const float* b = (const float*)d_in[4];
    float* out = (float*)d_out;

    const int N = in_sizes[0] / 128;
    const int E = in_sizes[1];

    // ws: hist[N] | cursor[N] | blockSums[512] | wT[16384 u16] | Xb[N*64 u32] | csr_src[E]
    char* wsb = (char*)d_ws;
    size_t off = 0;
    int* hist      = (int*)(wsb + off); off += (size_t)4 * N;
    int* cursor    = (int*)(wsb + off); off += (size_t)4 * N;
    int* blockSums = (int*)(wsb + off); off += 2048;
    unsigned short* wT = (unsigned short*)(wsb + off); off += 32768;
    off = (off + 255) & ~(size_t)255;
    unsigned int* Xb = (unsigned int*)(wsb + off); off += (size_t)N * 256;
    int* csr_src   = (int*)(wsb + off);

    const int nx2 = N * 64;              // float2 packs in X
    const int nbN = (N + 255) / 256;     // 391 (<=512 for scan2)
    const int nbE = (E + 255) / 256;

    prep_kernel<<<(nx2 + 255) / 256, 256, 0, stream>>>(X, w, Xb, wT, hist, N, nx2);
    hist_kernel<<<nbE, 256, 0, stream>>>(B, hist, E);
    scan1_kernel<<<nbN, 256, 0, stream>>>(hist, cursor, blockSums, N);
    scan2_kernel<<<1, 512, 0, stream>>>(blockSums, nbN);
    fill_kernel<<<nbE, 256, 0, stream>>>(A, B, cursor, blockSums, csr_src, E);
    aggemm_kernel<<<(N + 63) / 64, 256, 0, stream>>>(
        Xb, hist, cursor, blockSums, csr_src, wT, b, out, N);
}